// Round 7
// baseline (168.820 us; speedup 1.0000x reference)
//
#include <hip/hip_runtime.h>
#include <hip/hip_fp16.h>

// NCC loss, fully fused, R7: R6 structure + DC 40->20 (grid 1920, 6 blocks/CU
// resident by LDS) to fix grid-capped occupancy (33% -> ~60%+). fp16 (half2)
// wsum/hsum intermediates, 48-lane w-round, shift-by-2 ring, 2 barriers/macro.
// Vols: [B=2][D=160][H=192][W=160] fp32. Out: scalar -mean(cc).

#define B_    2
#define D_    160
#define H_    192
#define W_    160
#define HW_   (H_*W_)
#define SSTR  28
#define SSLC  (24*SSTR)            // 672
#define OFF_J (2*SSLC)             // 1344: raw J slices base
#define OFF_WS 2688                // end of raw region
#define WROW  10                   // wsum row stride (dw = half2 units)
#define WSLC2 240                  // wsum slice stride (24*10)
#define WFS2  486                  // wsum field stride (2*240+6), mod 32 = 6
#define OFF_HS (OFF_WS + 5*WFS2)   // 5118
#define HROW  10
#define HSLC2 160                  // hsum slice stride (16*10)
#define HFS2  326                  // hsum field stride (2*160+6), mod 32 = 6
#define OFF_RED (OFF_HS + 5*HFS2)  // 6748
#define SMEM_TOT (OFF_RED + 8)     // 6756 dw = 27.0 KB -> 6 blocks/CU
#define DC    20                   // d outputs per chunk (160/20 = 8 chunks)
#define NCHUNK (D_/DC)
#define NMAC  ((DC+8)/2)           // 14 macro steps
#define W3I   (1.0f/729.0f)
#define NTOT  9830400.0f

#if __has_builtin(__builtin_amdgcn_rcpf)
#define RCP(x) __builtin_amdgcn_rcpf(x)
#else
#define RCP(x) (1.0f/(x))
#endif

#define LGKM0() asm volatile("s_waitcnt lgkmcnt(0)" ::: "memory")

struct __align__(8) Half2x2 { __half2 a, b; };

// sliding 9-window along w: 12 inputs -> 4 outputs, packed to half2x2 (b64)
#define SLIDEX(EXPR, F) { \
  float v_[12]; \
  _Pragma("unroll") for (int k_ = 0; k_ < 12; ++k_) { v_[k_] = (EXPR); } \
  float s_ = v_[0]+v_[1]+v_[2]+v_[3]+v_[4]+v_[5]+v_[6]+v_[7]+v_[8]; \
  float4 o_; o_.x = s_; s_ += v_[9]-v_[0]; o_.y = s_; \
  s_ += v_[10]-v_[1]; o_.z = s_; s_ += v_[11]-v_[2]; o_.w = s_; \
  Half2x2 pk_; pk_.a = __floats2half2_rn(o_.x, o_.y); \
  pk_.b = __floats2half2_rn(o_.z, o_.w); \
  *(Half2x2*)&sm[wwr + (F)*WFS2] = pk_; }

__global__ __launch_bounds__(256, 4) void ncc_fused(const float* __restrict__ gI,
                                                    const float* __restrict__ gJ,
                                                    float* __restrict__ out)
{
  __shared__ __align__(16) float sm[SMEM_TOT];
  const int tid  = threadIdx.x;
  const int lane = tid & 63;
  const int Q    = tid >> 6;           // wave id = w-quad owner
  const int w0   = blockIdx.x * 16;
  const int h0   = blockIdx.y * 16;
  const int bz   = blockIdx.z;
  const int bb   = bz >> 3;                 // 8 chunks per batch
  const int d_lo = (bz & (NCHUNK-1)) * DC;

  // zero raw region once; invalid-hw slots stay 0 = 'same' zero pad
  for (int i = tid; i < OFF_WS; i += 256) sm[i] = 0.f;

  // ---------- staging task precompute: 288 tasks = 2 slc x 24 r x 6 quads ----
  bool val0 = false, val1 = false;
  int  lds0 = 0, lds1 = 0, slc0 = 0, slc1 = 0;
  const float *pi0 = gI, *pj0 = gJ, *pi1 = gI, *pj1 = gJ;
  {
    const int tA = tid;
    const int tB = (tid >= 224) ? (tid + 32) : 512;  // wave 3 takes 256..287
    auto prep = [&](int t, bool& val, int& lo, int& slc,
                    const float*& pi, const float*& pj) {
      if (t >= 288) { val = false; return; }
      slc = t / 144;
      const int u = t - slc*144;
      const int r = u / 6, c = u - r*6;
      const int gh = h0 - 4 + r;
      const int gw = w0 - 4 + 4*c;
      val = ((unsigned)gh < (unsigned)H_) && (gw >= 0) && (gw + 3 < W_);
      lo  = slc*SSLC + r*SSTR + 4*c;
      const long off = ((long)(bb*D_ + (d_lo - 4 + slc))*H_ + gh)*(long)W_ + gw;
      pi = gI + off; pj = gJ + off;
    };
    prep(tA, val0, lds0, slc0, pi0, pj0);
    prep(tB, val1, lds1, slc1, pi1, pj1);
  }

  // ---------- w-stage: 48 lanes = 2 slices x 24 rows ----------
  const bool wact = (lane < 48);
  const int  wslc = (lane >= 24) ? 1 : 0;
  const int  wrow = lane - 24*wslc;
  const int  wrd  = wslc*SSLC + wrow*SSTR + 4*Q;            // +OFF_J for J
  const int  wwr  = OFF_WS + wslc*WSLC2 + wrow*WROW + 2*Q;  // + f*WFS2

  // ---------- h-stage: 40 pair-tasks = 2 slc x 5 f x 2 half x 2 wpair ----
  const bool hact = (lane < 40);
  int hrd = 0, hwr = 0;
  {
    const int t     = hact ? lane : 0;
    const int wpair = t & 1;
    const int f     = (t >> 1) % 5;
    const int half  = (t / 10) & 1;
    const int slc   = t / 20;
    hrd = OFF_WS + f*WFS2 + slc*WSLC2 + half*(8*WROW) + 2*Q + wpair;  // +k*WROW
    hwr = OFF_HS + f*HFS2 + slc*HSLC2 + half*(8*HROW) + 2*Q + wpair;  // +j*HROW
  }

  // ---------- ring: lane -> (rh = lane>>2, w = 4Q + (lane&3)) ----------
  const int rh = lane >> 2, rwq = lane & 3;
  const int hb  = OFF_HS + rh*HROW + 2*Q + (rwq >> 1);   // + f*HFS2 (+HSLC2 for B)
  const int sh16 = (rwq & 1) * 16;                       // half-select shift

  float ring[5][9], S[5];
  #pragma unroll
  for (int f = 0; f < 5; ++f) {
    S[f] = 0.f;
    #pragma unroll
    for (int k = 0; k < 9; ++k) ring[f][k] = 0.f;
  }
  float acc = 0.f;

  // ---------- global prefetch ----------
  float4 f0i = {0,0,0,0}, f0j = {0,0,0,0}, f1i = {0,0,0,0}, f1j = {0,0,0,0};
  auto fetch = [&](int sbase) {
    if (val0 && (unsigned)(sbase + slc0) < (unsigned)D_) {
      f0i = *(const float4*)pi0; f0j = *(const float4*)pj0;
    } else { f0i = make_float4(0,0,0,0); f0j = make_float4(0,0,0,0); }
    pi0 += 2*HW_; pj0 += 2*HW_;
    if (val1 && (unsigned)(sbase + slc1) < (unsigned)D_) {
      f1i = *(const float4*)pi1; f1j = *(const float4*)pj1;
    } else { f1i = make_float4(0,0,0,0); f1j = make_float4(0,0,0,0); }
    pi1 += 2*HW_; pj1 += 2*HW_;
  };
  auto stage_write = [&]() {
    if (val0) { *(float4*)&sm[lds0] = f0i; *(float4*)&sm[lds0 + OFF_J] = f0j; }
    if (val1) { *(float4*)&sm[lds1] = f1i; *(float4*)&sm[lds1 + OFF_J] = f1j; }
  };

  auto h2ext = [&](int addr) -> float {   // read half2 word, extract own half
    const unsigned u = *(const unsigned*)&sm[addr];
    return __half2float(__ushort_as_half((unsigned short)(u >> sh16)));
  };

  fetch(d_lo - 4);        // macro 0's slices
  __syncthreads();        // zero-init visible
  stage_write();          // macro 0 raw
  __syncthreads();        // raw 0 ready

  int sA = d_lo - 4;
  for (int m = 0; m < NMAC; ++m, sA += 2) {
    if (m + 1 < NMAC) fetch(sA + 2);   // prefetch macro m+1 into regs

    // ---- w-stage: both slices, one 48-lane round, packed half2 writes ----
    if (wact) {
      const float4 a0 = *(const float4*)&sm[wrd];
      const float4 a1 = *(const float4*)&sm[wrd + 4];
      const float4 a2 = *(const float4*)&sm[wrd + 8];
      const float4 b0 = *(const float4*)&sm[wrd + OFF_J];
      const float4 b1 = *(const float4*)&sm[wrd + OFF_J + 4];
      const float4 b2 = *(const float4*)&sm[wrd + OFF_J + 8];
      const float wi[12] = {a0.x,a0.y,a0.z,a0.w,a1.x,a1.y,a1.z,a1.w,a2.x,a2.y,a2.z,a2.w};
      const float wj[12] = {b0.x,b0.y,b0.z,b0.w,b1.x,b1.y,b1.z,b1.w,b2.x,b2.y,b2.z,b2.w};
      SLIDEX(wi[k_],        0)
      SLIDEX(wj[k_],        1)
      SLIDEX(wi[k_]*wi[k_], 2)
      SLIDEX(wj[k_]*wj[k_], 3)
      SLIDEX(wi[k_]*wj[k_], 4)
    }
    LGKM0();   // wsum visible to own wave

    // ---- h-stage: packed half2, 2 w-columns per lane, 40 lanes ----
    if (hact) {
      __half2 v[16];
      #pragma unroll
      for (int k = 0; k < 16; ++k) v[k] = *(const __half2*)&sm[hrd + k*WROW];
      __half2 s = __hadd2(v[0], v[1]);
      s = __hadd2(s, v[2]); s = __hadd2(s, v[3]); s = __hadd2(s, v[4]);
      s = __hadd2(s, v[5]); s = __hadd2(s, v[6]); s = __hadd2(s, v[7]);
      s = __hadd2(s, v[8]);
      *(__half2*)&sm[hwr] = s;
      #pragma unroll
      for (int j = 1; j < 8; ++j) {
        s = __hsub2(__hadd2(s, v[j+8]), v[j-1]);
        *(__half2*)&sm[hwr + j*HROW] = s;
      }
    }
    LGKM0();   // hsum visible to own wave

    // ---- d-ring (shift by 2) + cc ----
    {
      float nA[5], nB[5];
      #pragma unroll
      for (int f = 0; f < 5; ++f) {
        nA[f] = h2ext(hb + f*HFS2);
        nB[f] = h2ext(hb + f*HFS2 + HSLC2);
      }
      float SA[5], SB[5];
      #pragma unroll
      for (int f = 0; f < 5; ++f) {
        SA[f] = S[f]  + nA[f] - ring[f][8];
        SB[f] = SA[f] + nB[f] - ring[f][7];
        S[f]  = SB[f];
        #pragma unroll
        for (int k = 8; k >= 2; --k) ring[f][k] = ring[f][k-2];
        ring[f][1] = nA[f]; ring[f][0] = nB[f];
      }
      if (m >= 4) {
        {
          const float cr = SA[4] - SA[0]*SA[1]*W3I;
          const float vi = SA[2] - SA[0]*SA[0]*W3I;
          const float vj = SA[3] - SA[1]*SA[1]*W3I;
          acc += cr*cr * RCP(vi*vj + 1e-5f);
        }
        {
          const float cr = SB[4] - SB[0]*SB[1]*W3I;
          const float vi = SB[2] - SB[0]*SB[0]*W3I;
          const float vj = SB[3] - SB[1]*SB[1]*W3I;
          acc += cr*cr * RCP(vi*vj + 1e-5f);
        }
      }
    }

    __syncthreads();                   // B1: raw reads of macro m done
    if (m + 1 < NMAC) stage_write();   // write macro m+1 raw
    __syncthreads();                   // B2: raw m+1 ready (drains lgkm)
  }

  // ---- block reduction -> single atomic ----
  float v = acc;
  #pragma unroll
  for (int off = 32; off > 0; off >>= 1)
    v += __shfl_down(v, off, 64);
  if (lane == 0) sm[OFF_RED + Q] = v;
  __syncthreads();
  if (tid == 0) {
    const float t = sm[OFF_RED] + sm[OFF_RED+1] + sm[OFF_RED+2] + sm[OFF_RED+3];
    atomicAdd(out, -t / NTOT);
  }
}

extern "C" void kernel_launch(void* const* d_in, const int* in_sizes, int n_in,
                              void* d_out, int out_size, void* d_ws, size_t ws_size,
                              hipStream_t stream) {
  const float* J = (const float*)d_in[0];  // y_pred
  const float* I = (const float*)d_in[1];  // y_true (cc symmetric in I,J)
  float* outp = (float*)d_out;
  hipMemsetAsync(d_out, 0, sizeof(float), stream);
  dim3 grid(W_/16, H_/16, B_*NCHUNK);      // 10 x 12 x 16 = 1920 blocks
  ncc_fused<<<grid, dim3(256), 0, stream>>>(I, J, outp);
}

// Round 8
// 147.512 us; speedup vs baseline: 1.1444x; 1.1444x over previous
//
#include <hip/hip_runtime.h>
#include <hip/hip_fp16.h>

// NCC loss, fully fused, R8: w/h box-sums moved to MFMA pipe.
// wsum = RAW_f[24x24+pad] x Sw[32x16], hsum = Sh[16x32] x wsum — both via
// v_mfma_f32_16x16x32_f16 with a shared constant banded 0/1 fragment SEL
// (Sw[k][n] = Sh[m][k-form] = [idx <= k <= idx+8]). Staging converts raw to
// fp16 and builds the 5 product fields with packed __hmul2. 10 chains
// (2 slc x 5 f) x 3 MFMAs per macro, spread over 4 waves. Ring unchanged.
// DC=40 (R2/R7: throughput-bound — minimize total block-macros).
// Vols: [B=2][D=160][H=192][W=160] fp32. Out: scalar -mean(cc).

#define B_    2
#define D_    160
#define H_    192
#define W_    160
#define HW_   (H_*W_)

// LDS layout (float-word offsets)
#define RS    20                   // raw row stride: 24 taps fp16 = 12 dw, pad->20
#define SLS   (24*RS)              // 480: raw slice stride
#define FS    (2*SLS)              // 960: raw field stride (2 slices)
#define ZROW  4800                 // 16 dw of zeros (A2 OOB-row reads)
#define TMP0  4816                 // 4 waves x 320
#define TS    20                   // tmp col stride (32 k fp16 = 16 dw, pad->20)
#define HSUM0 (TMP0 + 4*320)       // 6096: 10 chains x 160
#define HCS   160                  // per-(slc,f) hsum block: 16 cols x 10
#define HRS   10                   // hsum col stride (16 h fp16 = 8 dw, pad->10)
#define REDU  (HSUM0 + 10*HCS)     // 7696
#define SMEM  (REDU + 8)           // 7704 dw = 30.8 KB
#define DC    40
#define NMAC  24                   // (DC+8)/2
#define W3I   (1.0f/729.0f)
#define NTOT  9830400.0f

#if __has_builtin(__builtin_amdgcn_rcpf)
#define RCP(x) __builtin_amdgcn_rcpf(x)
#else
#define RCP(x) (1.0f/(x))
#endif
#define LGKM0() asm volatile("s_waitcnt lgkmcnt(0)" ::: "memory")

typedef _Float16 half8 __attribute__((ext_vector_type(8)));
typedef float    f32x4 __attribute__((ext_vector_type(4)));
#define MFMA16(a,b,c) __builtin_amdgcn_mfma_f32_16x16x32_f16((a),(b),(c),0,0,0)

struct __align__(8) HP { __half2 a, b; };   // 4 fp16 = one b64 LDS word-pair

__global__ __launch_bounds__(256, 4) void ncc_fused(const float* __restrict__ gI,
                                                    const float* __restrict__ gJ,
                                                    float* __restrict__ out)
{
  __shared__ __align__(16) float sm[SMEM];
  const int tid  = threadIdx.x;
  const int lane = tid & 63;
  const int Q    = tid >> 6;
  const int n15  = lane & 15;          // MFMA: A-row m / B-col n / D-col
  const int q4   = lane >> 4;          // MFMA: k-group / D-row quad
  const int w0   = blockIdx.x * 16;
  const int h0   = blockIdx.y * 16;
  const int bz   = blockIdx.z;
  const int bb   = bz >> 2;
  const int d_lo = (bz & 3) * DC;

  // zero raw region + zrow (pad taps 24..31 and invalid halo stay 0 forever)
  for (int i = tid; i < TMP0; i += 256) sm[i] = 0.f;

  // shared banded selection fragment: SEL[j] = [n15 <= k <= n15+8], k = 8*q4+j
  half8 SEL;
  #pragma unroll
  for (int j = 0; j < 8; ++j) {
    const int k = 8*q4 + j;
    SEL[j] = (k >= n15 && k <= n15 + 8) ? (_Float16)1 : (_Float16)0;
  }

  // ---------- staging: 288 tasks = 2 slc x 24 r x 6 quads ----------
  bool val0 = false, val1 = false;
  int  lo0 = 0, lo1 = 0, sc0 = 0, sc1 = 0;
  const float *pi0 = gI, *pj0 = gJ, *pi1 = gI, *pj1 = gJ;
  {
    auto prep = [&](int t, bool& val, int& lo, int& sc,
                    const float*& pi, const float*& pj) {
      if (t >= 288) { val = false; return; }
      sc = t / 144;
      const int u = t - sc*144;
      const int r = u / 6, c = u - r*6;
      const int gh = h0 - 4 + r, gw = w0 - 4 + 4*c;
      val = ((unsigned)gh < (unsigned)H_) && (gw >= 0) && (gw + 3 < W_);
      lo  = sc*SLS + r*RS + 2*c;
      const long off = ((long)(bb*D_ + (d_lo - 4 + sc))*H_ + gh)*(long)W_ + gw;
      pi = gI + off; pj = gJ + off;
    };
    prep(tid, val0, lo0, sc0, pi0, pj0);
    prep((tid >= 224) ? tid + 32 : 512, val1, lo1, sc1, pi1, pj1);
  }

  // ---------- chain bases: wave Q handles c = Q, Q+4, Q+8 (<10) ----------
  int rb_[3], hb_[3];
  #pragma unroll
  for (int i = 0; i < 3; ++i) {
    int c = Q + 4*i; if (c > 9) c = 9;          // clamped entry unused
    rb_[i] = (c % 5)*FS + (c / 5)*SLS;
    hb_[i] = HSUM0 + c*HCS;
  }
  const int tb  = TMP0 + Q*320 + n15*TS;
  const int a1r = n15*RS + 4*q4;
  const int a2r = (n15 < 8) ? ((16 + n15)*RS + 4*q4) : -1;
  const int zr  = ZROW + 4*q4;

  // ---------- ring: thread owns (h = tid>>4, w = tid&15) ----------
  const int rh = tid >> 4, rw = tid & 15;
  const int rbase = HSUM0 + rw*HRS + (rh >> 1);
  const int rsh   = (rh & 1) * 16;

  float ring[5][9], S[5];
  #pragma unroll
  for (int f = 0; f < 5; ++f) {
    S[f] = 0.f;
    #pragma unroll
    for (int k = 0; k < 9; ++k) ring[f][k] = 0.f;
  }
  float acc = 0.f;

  // ---------- global prefetch ----------
  float4 f0i = {0,0,0,0}, f0j = {0,0,0,0}, f1i = {0,0,0,0}, f1j = {0,0,0,0};
  auto fetch = [&](int sbase) {
    if (val0 && (unsigned)(sbase + sc0) < (unsigned)D_) {
      f0i = *(const float4*)pi0; f0j = *(const float4*)pj0;
    } else { f0i = make_float4(0,0,0,0); f0j = make_float4(0,0,0,0); }
    pi0 += 2*HW_; pj0 += 2*HW_;
    if (val1 && (unsigned)(sbase + sc1) < (unsigned)D_) {
      f1i = *(const float4*)pi1; f1j = *(const float4*)pj1;
    } else { f1i = make_float4(0,0,0,0); f1j = make_float4(0,0,0,0); }
    pi1 += 2*HW_; pj1 += 2*HW_;
  };

  auto stage_one = [&](int lo, float4 fi, float4 fj) {
    const __half2 i01 = __floats2half2_rn(fi.x, fi.y);
    const __half2 i23 = __floats2half2_rn(fi.z, fi.w);
    const __half2 j01 = __floats2half2_rn(fj.x, fj.y);
    const __half2 j23 = __floats2half2_rn(fj.z, fj.w);
    HP hI; hI.a = i01; hI.b = i23;
    HP hJ; hJ.a = j01; hJ.b = j23;
    HP h2; h2.a = __hmul2(i01, i01); h2.b = __hmul2(i23, i23);
    HP h3; h3.a = __hmul2(j01, j01); h3.b = __hmul2(j23, j23);
    HP h4; h4.a = __hmul2(i01, j01); h4.b = __hmul2(i23, j23);
    *(HP*)&sm[lo]        = hI;
    *(HP*)&sm[lo +   FS] = hJ;
    *(HP*)&sm[lo + 2*FS] = h2;
    *(HP*)&sm[lo + 3*FS] = h3;
    *(HP*)&sm[lo + 4*FS] = h4;
  };
  auto stage_write = [&]() {
    if (val0) stage_one(lo0, f0i, f0j);
    if (val1) stage_one(lo1, f1i, f1j);
  };

  // ---------- one chain: raw field slice -> hsum (2 w-MFMAs + 1 h-MFMA) ----
  auto chain = [&](int rb, int hb) {
    const half8 A1 = *(const half8*)&sm[rb + a1r];
    const half8 A2 = (a2r >= 0) ? *(const half8*)&sm[rb + a2r]
                                : *(const half8*)&sm[zr];
    const f32x4 z = {0.f, 0.f, 0.f, 0.f};
    const f32x4 d1 = MFMA16(A1, SEL, z);      // wsum rows 0..15
    const f32x4 d2 = MFMA16(A2, SEL, z);      // wsum rows 16..23 (24..31 = 0)
    HP p1; p1.a = __floats2half2_rn(d1[0], d1[1]); p1.b = __floats2half2_rn(d1[2], d1[3]);
    HP p2; p2.a = __floats2half2_rn(d2[0], d2[1]); p2.b = __floats2half2_rn(d2[2], d2[3]);
    *(HP*)&sm[tb + 2*q4]     = p1;            // tmp col n15, k = 4q4..4q4+3
    *(HP*)&sm[tb + 8 + 2*q4] = p2;            // k = 16+4q4..19+4q4
    LGKM0();                                  // tmp visible to own wave
    const half8 Bh = *(const half8*)&sm[tb + 4*q4];   // col n15, k = 8q4..8q4+7
    const f32x4 dh = MFMA16(SEL, Bh, z);      // hsum[m = h][n = w]
    HP ph; ph.a = __floats2half2_rn(dh[0], dh[1]); ph.b = __floats2half2_rn(dh[2], dh[3]);
    *(HP*)&sm[hb + n15*HRS + 2*q4] = ph;      // col w = n15, h = 4q4..4q4+3
  };

  auto h2ext = [&](int addr) -> float {
    const unsigned u = *(const unsigned*)&sm[addr];
    return __half2float(__ushort_as_half((unsigned short)(u >> rsh)));
  };
  auto ring_cc = [&](int m) {
    float nA[5], nB[5];
    #pragma unroll
    for (int f = 0; f < 5; ++f) {
      nA[f] = h2ext(rbase + f*HCS);           // slice A = chain f
      nB[f] = h2ext(rbase + (5 + f)*HCS);     // slice B = chain 5+f
    }
    float SA[5], SB[5];
    #pragma unroll
    for (int f = 0; f < 5; ++f) {
      SA[f] = S[f]  + nA[f] - ring[f][8];
      SB[f] = SA[f] + nB[f] - ring[f][7];
      S[f]  = SB[f];
      #pragma unroll
      for (int k = 8; k >= 2; --k) ring[f][k] = ring[f][k-2];
      ring[f][1] = nA[f]; ring[f][0] = nB[f];
    }
    if (m >= 4) {
      {
        const float cr = SA[4] - SA[0]*SA[1]*W3I;
        const float vi = SA[2] - SA[0]*SA[0]*W3I;
        const float vj = SA[3] - SA[1]*SA[1]*W3I;
        acc += cr*cr * RCP(vi*vj + 1e-5f);
      }
      {
        const float cr = SB[4] - SB[0]*SB[1]*W3I;
        const float vi = SB[2] - SB[0]*SB[0]*W3I;
        const float vj = SB[3] - SB[1]*SB[1]*W3I;
        acc += cr*cr * RCP(vi*vj + 1e-5f);
      }
    }
  };

  fetch(d_lo - 4);          // macro 0 slices
  __syncthreads();          // zero-init visible
  stage_write();            // raw macro 0
  fetch(d_lo - 2);          // macro 1 slices
  __syncthreads();          // raw 0 ready

  for (int m = 0; m < NMAC; ++m) {
    chain(rb_[0], hb_[0]);
    chain(rb_[1], hb_[1]);
    if (Q < 2) chain(rb_[2], hb_[2]);
    __syncthreads();                       // hsum (all waves) ready
    ring_cc(m);
    if (m + 1 < NMAC) { stage_write(); fetch(d_lo + 2*m); }  // raw m+1; regs m+2
    __syncthreads();                       // raw m+1 ready; hsum consumed
  }

  // ---- block reduction -> single atomic ----
  float v = acc;
  #pragma unroll
  for (int off = 32; off > 0; off >>= 1)
    v += __shfl_down(v, off, 64);
  if (lane == 0) sm[REDU + Q] = v;
  __syncthreads();
  if (tid == 0) {
    const float t = sm[REDU] + sm[REDU+1] + sm[REDU+2] + sm[REDU+3];
    atomicAdd(out, -t / NTOT);
  }
}

extern "C" void kernel_launch(void* const* d_in, const int* in_sizes, int n_in,
                              void* d_out, int out_size, void* d_ws, size_t ws_size,
                              hipStream_t stream) {
  const float* J = (const float*)d_in[0];  // y_pred
  const float* I = (const float*)d_in[1];  // y_true (cc symmetric in I,J)
  float* outp = (float*)d_out;
  hipMemsetAsync(d_out, 0, sizeof(float), stream);
  dim3 grid(W_/16, H_/16, B_*4);           // 10 x 12 x 8 = 960 blocks
  ncc_fused<<<grid, dim3(256), 0, stream>>>(I, J, outp);
}